// Round 9
// baseline (268.550 us; speedup 1.0000x reference)
//
#include <hip/hip_runtime.h>

// NEAT batched forward, genome-pipelined edition.
// R6 analysis: kernel was memory-latency/MLP-bound — each block issues its 13
// vector loads once (~13KB/wave) then computes ~10K cycles; avg outstanding
// bytes/CU ~2.6KB -> BW capped at ~1.2TB/s (measured, R3==R6). Fix: persistent
// blocks process GPB=4 genomes, double-buffered in two NAMED register structs;
// genome g+1's loads are issued during g's layer passes (~4-5K cy early).
// Slow path re-reads global (keeps CUR regs dead -> no pressure).

#define NN    256
#define NE    4096
#define NIN   64
#define NOUT  8
#define NT    256
#define NWAVE 4
#define CAP   2560   // live-edge capacity: E=1536, sd=31 -> 33 sigma margin
#define GPB   4      // genomes per block (B must be divisible; 4096/4=1024)

struct GenRegs {
    int4   a0, a1, a2, a3;   // conn_in
    int4   c0, c1, c2, c3;   // conn_out
    float4 w0, w1, w2, w3;   // conn_weight
    unsigned m;              // 16-bit enabled mask
};

__device__ __forceinline__ void load_genome(
    GenRegs& r, int t, size_t gi, bool byte_mode,
    const int* __restrict__ conn_in, const int* __restrict__ conn_out,
    const float* __restrict__ conn_w, const unsigned char* __restrict__ conn_en)
{
    const int4*   ci4 = (const int4*)(conn_in  + gi * NE);
    const int4*   co4 = (const int4*)(conn_out + gi * NE);
    const float4* w4  = (const float4*)(conn_w  + gi * NE);
    r.a0 = ci4[t];        r.a1 = ci4[t + NT];
    r.a2 = ci4[t + 2*NT]; r.a3 = ci4[t + 3*NT];
    r.c0 = co4[t];        r.c1 = co4[t + NT];
    r.c2 = co4[t + 2*NT]; r.c3 = co4[t + 3*NT];
    r.w0 = w4[t];         r.w1 = w4[t + NT];
    r.w2 = w4[t + 2*NT];  r.w3 = w4[t + 3*NT];
    unsigned m = 0;
    if (byte_mode) {
        const uchar4* e4 = (const uchar4*)(conn_en + gi * NE);
        uchar4 e0 = e4[t], e1 = e4[t + NT], e2 = e4[t + 2*NT], e3 = e4[t + 3*NT];
        m = (e0.x?1u<<0:0u)|(e0.y?1u<<1:0u)|(e0.z?1u<<2:0u)|(e0.w?1u<<3:0u)
          | (e1.x?1u<<4:0u)|(e1.y?1u<<5:0u)|(e1.z?1u<<6:0u)|(e1.w?1u<<7:0u)
          | (e2.x?1u<<8:0u)|(e2.y?1u<<9:0u)|(e2.z?1u<<10:0u)|(e2.w?1u<<11:0u)
          | (e3.x?1u<<12:0u)|(e3.y?1u<<13:0u)|(e3.z?1u<<14:0u)|(e3.w?1u<<15:0u);
    } else {
        const int4* e4 = (const int4*)((const int*)conn_en + gi * NE);
        int4 e0 = e4[t], e1 = e4[t + NT], e2 = e4[t + 2*NT], e3 = e4[t + 3*NT];
        m = (e0.x?1u<<0:0u)|(e0.y?1u<<1:0u)|(e0.z?1u<<2:0u)|(e0.w?1u<<3:0u)
          | (e1.x?1u<<4:0u)|(e1.y?1u<<5:0u)|(e1.z?1u<<6:0u)|(e1.w?1u<<7:0u)
          | (e2.x?1u<<8:0u)|(e2.y?1u<<9:0u)|(e2.z?1u<<10:0u)|(e2.w?1u<<11:0u)
          | (e3.x?1u<<12:0u)|(e3.y?1u<<13:0u)|(e3.z?1u<<14:0u)|(e3.w?1u<<15:0u);
    }
    r.m = m;
}

#define KEYSLOT(J, CO) { \
    int kk = (int)nl_sh[(CO)]; \
    kk = ((mm >> (J)) & 1u) ? kk : 0; \
    keys |= (unsigned)kk << (2*(J)); \
    c1n += (kk == 1); c2n += (kk == 2); c3n += (kk == 3); }

#define SCAT(J, CI, CO, W) { \
    int kk = (int)((keys >> (2*(J))) & 3u); \
    unsigned long long B1 = __ballot(kk == 1); \
    unsigned long long B2 = __ballot(kk == 2); \
    unsigned long long B3 = __ballot(kk == 3); \
    if (kk) { \
        unsigned long long bk = (kk == 1) ? B1 : ((kk == 2) ? B2 : B3); \
        int bs = (kk == 1) ? base1 : ((kk == 2) ? base2 : base3); \
        int pos = bs + __popcll(bk & lmlt); \
        edges[pos] = make_uint2(__float_as_uint(W), (unsigned)(CI) | ((unsigned)(CO) << 8)); \
    } \
    base1 += __popcll(B1); base2 += __popcll(B2); base3 += __popcll(B3); }

// One genome: init -> keys -> scan -> SCAT -> (prefetch NXT) -> layer passes -> out
#define PROCESS(GOFF, CUR, NXT, DO_PRE)                                          \
{                                                                                \
    const size_t gi = g0 + (GOFF);                                               \
    const int   nl    = node_layer[gi * NN + t];                                 \
    const float vinit = (t < NIN) ? inputs[gi * NIN + t] : 0.0f;                 \
    nl_sh[t] = (unsigned char)nl;                                                \
    vals[t]  = vinit;                                                            \
    agg[t]   = 0.0f;                                                             \
    __syncthreads();                                                             \
    const unsigned mm = CUR.m;                                                   \
    unsigned keys = 0;                                                           \
    int c1n = 0, c2n = 0, c3n = 0;                                               \
    KEYSLOT(0,  CUR.c0.x) KEYSLOT(1,  CUR.c0.y) KEYSLOT(2,  CUR.c0.z) KEYSLOT(3,  CUR.c0.w) \
    KEYSLOT(4,  CUR.c1.x) KEYSLOT(5,  CUR.c1.y) KEYSLOT(6,  CUR.c1.z) KEYSLOT(7,  CUR.c1.w) \
    KEYSLOT(8,  CUR.c2.x) KEYSLOT(9,  CUR.c2.y) KEYSLOT(10, CUR.c2.z) KEYSLOT(11, CUR.c2.w) \
    KEYSLOT(12, CUR.c3.x) KEYSLOT(13, CUR.c3.y) KEYSLOT(14, CUR.c3.z) KEYSLOT(15, CUR.c3.w) \
    _Pragma("unroll")                                                            \
    for (int off = 32; off > 0; off >>= 1) {                                     \
        c1n += __shfl_down(c1n, off);                                            \
        c2n += __shfl_down(c2n, off);                                            \
        c3n += __shfl_down(c3n, off);                                            \
    }                                                                            \
    if (lane == 0) { wave_cnt[wave][0] = c1n; wave_cnt[wave][1] = c2n; wave_cnt[wave][2] = c3n; } \
    __syncthreads();                                                             \
    int T1 = 0, T2 = 0, T3 = 0, p1 = 0, p2 = 0, p3 = 0;                          \
    _Pragma("unroll")                                                            \
    for (int w = 0; w < NWAVE; ++w) {                                            \
        const int x = wave_cnt[w][0], y = wave_cnt[w][1], z = wave_cnt[w][2];    \
        if (w < wave) { p1 += x; p2 += y; p3 += z; }                             \
        T1 += x; T2 += y; T3 += z;                                               \
    }                                                                            \
    const int  total = T1 + T2 + T3;                                             \
    const bool fastp = (total <= CAP);                                           \
    if (fastp) {                                                                 \
        int base1 = p1, base2 = T1 + p2, base3 = T1 + T2 + p3;                   \
        SCAT(0,  CUR.a0.x, CUR.c0.x, CUR.w0.x) SCAT(1,  CUR.a0.y, CUR.c0.y, CUR.w0.y) \
        SCAT(2,  CUR.a0.z, CUR.c0.z, CUR.w0.z) SCAT(3,  CUR.a0.w, CUR.c0.w, CUR.w0.w) \
        SCAT(4,  CUR.a1.x, CUR.c1.x, CUR.w1.x) SCAT(5,  CUR.a1.y, CUR.c1.y, CUR.w1.y) \
        SCAT(6,  CUR.a1.z, CUR.c1.z, CUR.w1.z) SCAT(7,  CUR.a1.w, CUR.c1.w, CUR.w1.w) \
        SCAT(8,  CUR.a2.x, CUR.c2.x, CUR.w2.x) SCAT(9,  CUR.a2.y, CUR.c2.y, CUR.w2.y) \
        SCAT(10, CUR.a2.z, CUR.c2.z, CUR.w2.z) SCAT(11, CUR.a2.w, CUR.c2.w, CUR.w2.w) \
        SCAT(12, CUR.a3.x, CUR.c3.x, CUR.w3.x) SCAT(13, CUR.a3.y, CUR.c3.y, CUR.w3.y) \
        SCAT(14, CUR.a3.z, CUR.c3.z, CUR.w3.z) SCAT(15, CUR.a3.w, CUR.c3.w, CUR.w3.w) \
    }                                                                            \
    if (DO_PRE)  /* prefetch next genome: CUR regs now dead, loads hide under layers */ \
        load_genome(NXT, t, gi + 1, byte_mode, conn_in, conn_out, conn_w, conn_en); \
    __syncthreads();   /* edges ready */                                         \
    float vreg = vinit;                                                          \
    if (fastp) {                                                                 \
        _Pragma("unroll")                                                        \
        for (int L = 1; L < 4; ++L) {                                            \
            const int s = (L == 1) ? 0  : ((L == 2) ? T1 : T1 + T2);             \
            const int e = (L == 1) ? T1 : ((L == 2) ? T1 + T2 : total);          \
            for (int p = s + t; p < e; p += NT) {                                \
                const uint2 ed = edges[p];                                       \
                atomicAdd(&agg[ed.y >> 8], vals[ed.y & 0xFFu] * __uint_as_float(ed.x)); \
            }                                                                    \
            __syncthreads();                                                     \
            const float u = agg[t];                                              \
            if (nl == L) { vreg = tanhf(u); vals[t] = vreg; }                    \
            agg[t] = 0.0f;                                                       \
            if (L < 3) __syncthreads();                                          \
        }                                                                        \
    } else {                                                                     \
        /* never taken on real data: re-read globals (keeps CUR dead) */         \
        _Pragma("unroll")                                                        \
        for (int L = 1; L < 4; ++L) {                                            \
            for (int e2 = t; e2 < NE; e2 += NT) {                                \
                const size_t eo = gi * (size_t)NE + e2;                          \
                const bool en = byte_mode ? (conn_en[eo] != 0)                   \
                                          : (((const int*)conn_en)[eo] != 0);    \
                if (en) {                                                        \
                    const int co = conn_out[eo];                                 \
                    if ((int)nl_sh[co] == L)                                     \
                        atomicAdd(&agg[co], vals[conn_in[eo]] * conn_w[eo]);     \
                }                                                                \
            }                                                                    \
            __syncthreads();                                                     \
            const float u = agg[t];                                              \
            if (nl == L) { vreg = tanhf(u); vals[t] = vreg; }                    \
            agg[t] = 0.0f;                                                       \
            if (L < 3) __syncthreads();                                          \
        }                                                                        \
    }                                                                            \
    if (t >= NIN && t < NIN + NOUT)                                              \
        out[gi * NOUT + (t - NIN)] = vreg;                                       \
}

__global__ __launch_bounds__(NT) void neat_fwd(
    const float* __restrict__ inputs,          // [B,64]
    const int*   __restrict__ node_layer,      // [B,256]
    const int*   __restrict__ conn_in,         // [B,4096]
    const int*   __restrict__ conn_out,        // [B,4096]
    const float* __restrict__ conn_w,          // [B,4096]
    const unsigned char* __restrict__ conn_en, // [B,4096] bool (layout sniffed)
    float*       __restrict__ out)             // [B,8]
{
    const int t    = threadIdx.x;
    const int wave = t >> 6;
    const int lane = t & 63;
    const unsigned long long lmlt = (1ull << lane) - 1ull;
    const size_t g0 = (size_t)blockIdx.x * GPB;

    __shared__ float          vals[NN];
    __shared__ float          agg[NN];
    __shared__ unsigned char  nl_sh[NN];
    __shared__ uint2          edges[CAP];      // {w, src|(tgt<<8)} bucketed by layer
    __shared__ int            wave_cnt[NWAVE][3];

    // sniff conn_enabled width once per block (uniform): byte bools vs int32
    const unsigned int* en_w = (const unsigned int*)(conn_en + g0 * NE);
    bool byte_mode = false;
#pragma unroll
    for (int i = 0; i < 16; ++i) byte_mode |= (en_w[i] > 1u);

    GenRegs rA, rB;
    load_genome(rA, t, g0, byte_mode, conn_in, conn_out, conn_w, conn_en);
    PROCESS(0, rA, rB, 1)
    PROCESS(1, rB, rA, 1)
    PROCESS(2, rA, rB, 1)
    PROCESS(3, rB, rA, 0)
}

extern "C" void kernel_launch(void* const* d_in, const int* in_sizes, int n_in,
                              void* d_out, int out_size, void* d_ws, size_t ws_size,
                              hipStream_t stream) {
    const float* inputs          = (const float*)d_in[0];
    const int*   node_layer      = (const int*)d_in[1];
    const int*   conn_in         = (const int*)d_in[2];
    const int*   conn_out        = (const int*)d_in[3];
    const float* conn_w          = (const float*)d_in[4];
    const unsigned char* conn_en = (const unsigned char*)d_in[5];
    float* out = (float*)d_out;

    const int B = in_sizes[0] / NIN;   // 4096 (assumed divisible by GPB)
    neat_fwd<<<B / GPB, NT, 0, stream>>>(inputs, node_layer, conn_in, conn_out,
                                         conn_w, conn_en, out);
}